// Round 1
// baseline (66.438 us; speedup 1.0000x reference)
//
#include <hip/hip_runtime.h>
#include <math.h>

#define B_   2
#define CTX_ 512
#define C_   16
#define RS_  16
#define RT_  16
#define T_   34      // 2 + 2*RT
#define L_   128     // isqrt(CTX*C*2)
#define K_   11      // isqrt(L)
#define H_   1024
#define EPS_ 1e-12f

__device__ __forceinline__ float siglog(float v) {
    return copysignf(log1pf(fabsf(v)), v);
}

// ---------------- Kernel 1: xt = x@W + b; xm; x2 = (xr+ixi)^2 ----------------
__global__ __launch_bounds__(512) void k_ctx(const float* __restrict__ x,
                                             const float* __restrict__ Wc,
                                             const float* __restrict__ bc,
                                             float2* __restrict__ x2out) {
    __shared__ float xrow[CTX_];
    __shared__ float xt[4 * L_];   // 512
    const int b = blockIdx.x;
    const int tid = threadIdx.x;
    xrow[tid] = x[b * CTX_ + tid];
    __syncthreads();
    float sum = bc[tid];
#pragma unroll 8
    for (int c = 0; c < CTX_; ++c)
        sum = fmaf(xrow[c], Wc[c * (4 * L_) + tid], sum);
    xt[tid] = sum;
    __syncthreads();
    if (tid < L_) {
        float xr = xt[2 * tid]     * siglog(xt[2 * L_ + 2 * tid]);
        float xi = xt[2 * tid + 1] * siglog(xt[2 * L_ + 2 * tid + 1]);
        x2out[b * L_ + tid] = make_float2(xr * xr - xi * xi, 2.0f * xr * xi);
    }
}

// ---------------- Kernel 2: per (t,c): AB contraction + L-reduction → tr ------
// block = (t*C + c); 256 threads = 16 r  x 16 l-groups (each handles 8 l's)
__global__ __launch_bounds__(256) void k_tr(const float2* __restrict__ A2,
                                            const float2* __restrict__ B2,
                                            const float2* __restrict__ x2,
                                            float2* __restrict__ tr2) {
    const int blk = blockIdx.x;
    const int tid = threadIdx.x;
    const int r  = tid & 15;
    const int lg = tid >> 4;

    __shared__ float sxr[B_][L_];
    __shared__ float sxi[B_][L_];
    {
        // B_*L_ = 256 float2's, one per thread
        float2 v = x2[tid];
        sxr[tid >> 7][tid & 127] = v.x;
        sxi[tid >> 7][tid & 127] = v.y;
    }
    __syncthreads();

    const float2* __restrict__ Ab = A2 + (size_t)blk * (L_ * K_ * RS_);
    const float2* __restrict__ Bb = B2 + (size_t)blk * (K_ * L_ * RS_);

    float sRe[B_] = {0.f, 0.f}, sIm[B_] = {0.f, 0.f}, sM[B_] = {0.f, 0.f};

    for (int j = 0; j < L_ / 16; ++j) {
        const int l = lg + 16 * j;
        float abr = 0.f, abi = 0.f;
#pragma unroll
        for (int k = 0; k < K_; ++k) {
            float2 a  = Ab[(l * K_ + k) * RS_ + r];
            float2 bv = Bb[(k * L_ + l) * RS_ + r];
            abr = fmaf(a.x, bv.x, abr);
            abr = fmaf(-a.y, bv.y, abr);
            abi = fmaf(a.x, bv.y, abi);
            abi = fmaf(a.y, bv.x, abi);
        }
#pragma unroll
        for (int b = 0; b < B_; ++b) {
            float xr2 = sxr[b][l], xi2 = sxi[b][l];
            float Re = xr2 * abr - xi2 * abi;
            float Im = xr2 * abi + xi2 * abr;
            float mag = sqrtf(fmaf(Re, Re, fmaf(Im, Im, EPS_)));
            sRe[b] += Re; sIm[b] += Im; sM[b] += mag;
        }
    }

    __shared__ float red[16][16][6];
    red[lg][r][0] = sRe[0]; red[lg][r][1] = sIm[0]; red[lg][r][2] = sM[0];
    red[lg][r][3] = sRe[1]; red[lg][r][4] = sIm[1]; red[lg][r][5] = sM[1];
    __syncthreads();

    if (tid < 2 * RS_) {
        const int b = tid >> 4, rr = tid & 15;
        float a0 = 0.f, a1 = 0.f, a2 = 0.f;
#pragma unroll
        for (int g = 0; g < 16; ++g) {
            a0 += red[g][rr][b * 3 + 0];
            a1 += red[g][rr][b * 3 + 1];
            a2 += red[g][rr][b * 3 + 2];
        }
        // cosw*mag_mean = (a0/(a2+EPS)) * (a2/L); same for sin
        const float inv = a2 / ((a2 + EPS_) * (float)L_);
        const int t = blk / C_, c = blk % C_;
        tr2[(((size_t)b * T_ + t) * C_ + c) * RS_ + rr] = make_float2(a0 * inv, a1 * inv);
    }
}

// ---------------- Kernel 3: apply_space (interp RT->H, complex combine) -------
__global__ __launch_bounds__(256) void k_out(const float2* __restrict__ space_i,
                                             const float2* __restrict__ space_j,
                                             const float2* __restrict__ tr2,
                                             float2* __restrict__ out) {
    const int half = B_ * C_ * RS_ * H_;   // 524288
    int idx = blockIdx.x * blockDim.x + threadIdx.x;
    if (idx >= 2 * half) return;
    const int which = (idx >= half) ? 1 : 0;
    int id = idx - which * half;

    const int h = id & (H_ - 1);
    int rest = id >> 10;
    const int r = rest & 15; rest >>= 4;
    const int c = rest & 15;
    const int b = rest >> 4;

    const float2* __restrict__ sp2 = which ? space_j : space_i;

    // tr index helper: ((b*T + t)*C + c)*RS + r
    const size_t trb = (((size_t)b * T_) * C_ + c) * RS_ + r;
    const size_t trs = (size_t)C_ * RS_;   // stride per t

    const float2 sh = tr2[trb + (size_t)which * trs];

    // linear interp along RT (16 -> 1024), align_corners=False
    float pos = (h + 0.5f) * (16.0f / 1024.0f) - 0.5f;
    pos = fminf(fmaxf(pos, 0.0f), 15.0f);
    const int i0 = (int)floorf(pos);
    const int i1 = min(i0 + 1, RT_ - 1);
    const float w = pos - (float)i0;

    const int tb = 2 + which * RT_;
    const float2 z0 = tr2[trb + (size_t)(tb + i0) * trs];
    const float2 z1 = tr2[trb + (size_t)(tb + i1) * trs];
    const float zx = z0.x * (1.0f - w) + z1.x * w;
    const float zy = z0.y * (1.0f - w) + z1.y * w;

    const float2 sv = sp2[((size_t)c * RS_ + r) * H_ + h];
    const float sx = sv.x + sh.x;
    const float sy = sv.y + sh.y;

    out[idx] = make_float2(sy * zy - sx * zx, sx * zy + sy * zx);
}

extern "C" void kernel_launch(void* const* d_in, const int* in_sizes, int n_in,
                              void* d_out, int out_size, void* d_ws, size_t ws_size,
                              hipStream_t stream) {
    const float*  x  = (const float*)d_in[0];
    const float*  Wc = (const float*)d_in[1];
    const float*  bc = (const float*)d_in[2];
    const float2* A2 = (const float2*)d_in[3];
    const float2* B2 = (const float2*)d_in[4];
    const float2* si = (const float2*)d_in[5];
    const float2* sj = (const float2*)d_in[6];

    float2* x2  = (float2*)d_ws;                       // B*L float2   (2 KB)
    float2* tr2 = (float2*)((char*)d_ws + 4096);       // B*T*C*RS float2 (139 KB)

    k_ctx<<<B_, 512, 0, stream>>>(x, Wc, bc, x2);
    k_tr<<<T_ * C_, 256, 0, stream>>>(A2, B2, x2, tr2);

    const int total = 2 * B_ * C_ * RS_ * H_;
    k_out<<<(total + 255) / 256, 256, 0, stream>>>(si, sj, tr2, (float2*)d_out);
}

// Round 2
// 66.055 us; speedup vs baseline: 1.0058x; 1.0058x over previous
//
#include <hip/hip_runtime.h>
#include <math.h>

#define B_   2
#define CTX_ 512
#define C_   16
#define RS_  16
#define RT_  16
#define T_   34      // 2 + 2*RT
#define L_   128
#define K_   11
#define H_   1024
#define EPS_ 1e-12f

#define NSPLIT_ 4
#define LCHUNK_ 32   // L_ / NSPLIT_

__device__ __forceinline__ float siglog(float v) {
    return copysignf(log1pf(fabsf(v)), v);
}

// ---------------- Kernel 1: xt = x@W + b; xm; x2 = (xr+ixi)^2 ----------------
__global__ __launch_bounds__(512) void k_ctx(const float* __restrict__ x,
                                             const float* __restrict__ Wc,
                                             const float* __restrict__ bc,
                                             float2* __restrict__ x2out) {
    __shared__ float xrow[CTX_];
    __shared__ float xt[4 * L_];
    const int b = blockIdx.x;
    const int tid = threadIdx.x;
    xrow[tid] = x[b * CTX_ + tid];
    __syncthreads();
    float sum = bc[tid];
#pragma unroll 8
    for (int c = 0; c < CTX_; ++c)
        sum = fmaf(xrow[c], Wc[c * (4 * L_) + tid], sum);
    xt[tid] = sum;
    __syncthreads();
    if (tid < L_) {
        float xr = xt[2 * tid]     * siglog(xt[2 * L_ + 2 * tid]);
        float xi = xt[2 * tid + 1] * siglog(xt[2 * L_ + 2 * tid + 1]);
        x2out[b * L_ + tid] = make_float2(xr * xr - xi * xi, 2.0f * xr * xi);
    }
}

// ---------------- Kernel 2a: partial AB contraction over an L-chunk ----------
// grid = T*C*NSPLIT; block = 256 = 4 waves; wave lane = rp(0..7) + 8*lw(0..7);
// each thread owns one l = l0 + (tid>>3) and an r-pair (2*rp, 2*rp+1).
__global__ __launch_bounds__(256) void k_tr_part(const float4* __restrict__ A4,
                                                 const float4* __restrict__ B4,
                                                 const float2* __restrict__ x2,
                                                 float* __restrict__ part) {
    const int blk = blockIdx.x;
    const int tc  = blk / NSPLIT_;
    const int s   = blk % NSPLIT_;
    const int tid = threadIdx.x;
    const int rp  = tid & 7;
    const int l   = s * LCHUNK_ + (tid >> 3);

    // float4 element index: ((tc*L + l)*K + k)*8 + rp   (A)
    //                       ((tc*K + k)*L + l)*8 + rp   (B)
    const float4* __restrict__ Ab = A4 + ((size_t)(tc * L_ + l) * K_) * 8 + rp;
    const float4* __restrict__ Bb = B4 + ((size_t)tc * K_ * L_ + l) * 8 + rp;

    float abr0 = 0.f, abi0 = 0.f, abr1 = 0.f, abi1 = 0.f;
#pragma unroll
    for (int k = 0; k < K_; ++k) {
        float4 a  = Ab[(size_t)k * 8];
        float4 bv = Bb[(size_t)k * L_ * 8];
        abr0 = fmaf(a.x, bv.x, abr0); abr0 = fmaf(-a.y, bv.y, abr0);
        abi0 = fmaf(a.x, bv.y, abi0); abi0 = fmaf( a.y, bv.x, abi0);
        abr1 = fmaf(a.z, bv.z, abr1); abr1 = fmaf(-a.w, bv.w, abr1);
        abi1 = fmaf(a.z, bv.w, abi1); abi1 = fmaf( a.w, bv.z, abi1);
    }

    // 12 accumulators: [b][pair][{Re,Im,M}]
    float acc[12];
#pragma unroll
    for (int b = 0; b < B_; ++b) {
        float2 xv = x2[b * L_ + l];
        float Re0 = xv.x * abr0 - xv.y * abi0;
        float Im0 = xv.x * abi0 + xv.y * abr0;
        float Re1 = xv.x * abr1 - xv.y * abi1;
        float Im1 = xv.x * abi1 + xv.y * abr1;
        acc[b * 6 + 0] = Re0;
        acc[b * 6 + 1] = Im0;
        acc[b * 6 + 2] = sqrtf(fmaf(Re0, Re0, fmaf(Im0, Im0, EPS_)));
        acc[b * 6 + 3] = Re1;
        acc[b * 6 + 4] = Im1;
        acc[b * 6 + 5] = sqrtf(fmaf(Re1, Re1, fmaf(Im1, Im1, EPS_)));
    }

    // butterfly over the 8 l's within the wave (lane bits 3,4,5)
#pragma unroll
    for (int off = 8; off <= 32; off <<= 1) {
#pragma unroll
        for (int i = 0; i < 12; ++i)
            acc[i] += __shfl_xor(acc[i], off);
    }

    __shared__ float wred[4][8][12];
    const int wave = tid >> 6;
    const int lane = tid & 63;
    if (lane < 8) {
#pragma unroll
        for (int i = 0; i < 12; ++i) wred[wave][lane][i] = acc[i];
    }
    __syncthreads();

    // 96 outputs: comp = (b*2+pair)*3 + c3, r = 2*rp + pair
    if (tid < 96) {
        const int rp2  = tid >> 2;          // wrong stride; recompute below
    }
    if (tid < 96) {
        const int rpi  = tid / 12;          // 0..7
        const int comp = tid % 12;          // (b*2+pair)*3 + c3
        float v = wred[0][rpi][comp] + wred[1][rpi][comp]
                + wred[2][rpi][comp] + wred[3][rpi][comp];
        const int b    = comp / 6;
        const int pair = (comp / 3) & 1;
        const int c3   = comp % 3;
        const int r    = 2 * rpi + pair;
        part[(((size_t)blk * B_ + b) * RS_ + r) * 3 + c3] = v;
    }
}

// ---------------- Kernel 2b: finalize -> tr ----------------------------------
__global__ __launch_bounds__(256) void k_tr_fin(const float* __restrict__ part,
                                                float2* __restrict__ tr2) {
    const int idx = blockIdx.x * blockDim.x + threadIdx.x;
    const int total = T_ * C_ * B_ * RS_;   // 17408
    if (idx >= total) return;
    const int r  = idx & 15;
    const int b  = (idx >> 4) & 1;
    const int tc = idx >> 5;

    float a0 = 0.f, a1 = 0.f, a2 = 0.f;
#pragma unroll
    for (int s = 0; s < NSPLIT_; ++s) {
        const size_t base = (((size_t)(tc * NSPLIT_ + s) * B_ + b) * RS_ + r) * 3;
        a0 += part[base + 0];
        a1 += part[base + 1];
        a2 += part[base + 2];
    }
    const float inv = a2 / ((a2 + EPS_) * (float)L_);
    const int t = tc / C_, c = tc % C_;
    tr2[(((size_t)b * T_ + t) * C_ + c) * RS_ + r] = make_float2(a0 * inv, a1 * inv);
}

// ---------------- Kernel 3: apply_space (interp RT->H, complex combine) ------
__global__ __launch_bounds__(256) void k_out(const float2* __restrict__ space_i,
                                             const float2* __restrict__ space_j,
                                             const float2* __restrict__ tr2,
                                             float2* __restrict__ out) {
    const int half = B_ * C_ * RS_ * H_;   // 524288
    int idx = blockIdx.x * blockDim.x + threadIdx.x;
    if (idx >= 2 * half) return;
    const int which = (idx >= half) ? 1 : 0;
    int id = idx - which * half;

    const int h = id & (H_ - 1);
    int rest = id >> 10;
    const int r = rest & 15; rest >>= 4;
    const int c = rest & 15;
    const int b = rest >> 4;

    const float2* __restrict__ sp2 = which ? space_j : space_i;

    const size_t trb = (((size_t)b * T_) * C_ + c) * RS_ + r;
    const size_t trs = (size_t)C_ * RS_;

    const float2 sh = tr2[trb + (size_t)which * trs];

    float pos = (h + 0.5f) * (16.0f / 1024.0f) - 0.5f;
    pos = fminf(fmaxf(pos, 0.0f), 15.0f);
    const int i0 = (int)floorf(pos);
    const int i1 = min(i0 + 1, RT_ - 1);
    const float w = pos - (float)i0;

    const int tb = 2 + which * RT_;
    const float2 z0 = tr2[trb + (size_t)(tb + i0) * trs];
    const float2 z1 = tr2[trb + (size_t)(tb + i1) * trs];
    const float zx = z0.x * (1.0f - w) + z1.x * w;
    const float zy = z0.y * (1.0f - w) + z1.y * w;

    const float2 sv = sp2[((size_t)c * RS_ + r) * H_ + h];
    const float sx = sv.x + sh.x;
    const float sy = sv.y + sh.y;

    out[idx] = make_float2(sy * zy - sx * zx, sx * zy + sy * zx);
}

extern "C" void kernel_launch(void* const* d_in, const int* in_sizes, int n_in,
                              void* d_out, int out_size, void* d_ws, size_t ws_size,
                              hipStream_t stream) {
    const float*  x  = (const float*)d_in[0];
    const float*  Wc = (const float*)d_in[1];
    const float*  bc = (const float*)d_in[2];
    const float4* A4 = (const float4*)d_in[3];
    const float4* B4 = (const float4*)d_in[4];
    const float2* si = (const float2*)d_in[5];
    const float2* sj = (const float2*)d_in[6];

    float2* x2   = (float2*)d_ws;                               // 2 KB
    float*  part = (float*)((char*)d_ws + 4096);                // 544*4*96*4 = 835 KB
    float2* tr2  = (float2*)((char*)d_ws + 4096 + 1024 * 1024); // 139 KB

    k_ctx<<<B_, 512, 0, stream>>>(x, Wc, bc, x2);

    k_tr_part<<<T_ * C_ * NSPLIT_, 256, 0, stream>>>(A4, B4, x2, part);

    const int fin_total = T_ * C_ * B_ * RS_;
    k_tr_fin<<<(fin_total + 255) / 256, 256, 0, stream>>>(part, tr2);

    const int total = 2 * B_ * C_ * RS_ * H_;
    k_out<<<(total + 255) / 256, 256, 0, stream>>>(si, sj, tr2, (float2*)d_out);
}